// Round 2
// baseline (494.810 us; speedup 1.0000x reference)
//
#include <hip/hip_runtime.h>
#include <hip/hip_bf16.h>

#define D_S 128

// ---------------------------------------------------------------------------
// Kernel 1: per-node precompute of the fused first layer.
//   AB[n][k]     = dot(W1[k, 0:128],   s[n]) + b1[k]   for k in [0,128)
//   AB[n][128+k] = dot(W1[k, 128:256], s[n])           for k in [0,128)
// 1 thread = 1 node (block = 1 wave = 64 nodes). Each thread keeps its s-row
// in 32 float4 registers and loops over all 256 outputs in chunks of 32.
// Chunks are transposed through LDS so global stores are lane-contiguous
// (old version: per-lane stride-1024B stores -> 10x HBM write amplification).
// W1 addresses are wave-uniform (k uniform) -> scalar loads + SGPR-operand FMA.
// ---------------------------------------------------------------------------
__global__ __launch_bounds__(64) void precompute_ab(
    const float* __restrict__ s, const float* __restrict__ W1,
    const float* __restrict__ b1, float* __restrict__ AB, int n_nodes) {
  __shared__ float tile[64][33];  // +1 pad: transposed read is conflict-free
  int lane = threadIdx.x;
  int n0 = blockIdx.x * 64;
  int n = n0 + lane;
  bool valid = (n < n_nodes);
  int nc = valid ? n : 0;

  // Whole s-row in registers (read once per node for all 256 outputs).
  float4 sr[32];
  const float4* sp = (const float4*)(s + (size_t)nc * D_S);
#pragma unroll
  for (int i = 0; i < 32; ++i) sr[i] = sp[i];

#pragma unroll 1
  for (int k0 = 0; k0 < 256; k0 += 32) {
    // ---- compute this thread's 32 outputs for chunk [k0, k0+32) ----
#pragma unroll 1
    for (int kk = 0; kk < 32; kk += 4) {
#pragma unroll
      for (int q = 0; q < 4; ++q) {
        int k = k0 + kk + q;  // wave-uniform
        const float* w = W1 + ((k < D_S) ? (size_t)k * (2 * D_S)
                                         : (size_t)(k - D_S) * (2 * D_S) + D_S);
        float a0 = 0.f, a1 = 0.f, a2 = 0.f, a3 = 0.f;
#pragma unroll
        for (int i = 0; i < 32; ++i) {
          a0 += sr[i].x * w[4 * i + 0];
          a1 += sr[i].y * w[4 * i + 1];
          a2 += sr[i].z * w[4 * i + 2];
          a3 += sr[i].w * w[4 * i + 3];
        }
        float acc = (a0 + a1) + (a2 + a3);
        if (k < D_S) acc += b1[k];
        tile[lane][kk + q] = acc;
      }
    }
    __syncthreads();
    // ---- transposed, coalesced store: lanes 0-31 -> node p (k consecutive),
    //      lanes 32-63 -> node p+1. Two 128B segments per store instr. ----
#pragma unroll
    for (int p = 0; p < 64; p += 2) {
      int hi = lane >> 5;
      int node = n0 + p + hi;
      float v = tile[p + hi][lane & 31];
      if (node < n_nodes) AB[(size_t)node * 256 + k0 + (lane & 31)] = v;
    }
    __syncthreads();
  }
}

// ---------------------------------------------------------------------------
// Kernel 2: per-edge. One wave (64 lanes) per edge.
//   out[e] = sum_k W2[k] * silu(AB[row][k] + AB[col][128+k]) + b2
// Lane l handles k = 2l, 2l+1 (coalesced float2 loads: 512B per row-half).
// ---------------------------------------------------------------------------
__global__ __launch_bounds__(256) void edge_kernel(
    const int* __restrict__ ei, const float* __restrict__ AB,
    const float* __restrict__ W2, const float* __restrict__ b2,
    float* __restrict__ out, int E) {
  int wave = (blockIdx.x * blockDim.x + threadIdx.x) >> 6;
  int lane = threadIdx.x & 63;
  if (wave >= E) return;
  int e = wave;

  int row = __builtin_amdgcn_readfirstlane(ei[e]);
  int col = __builtin_amdgcn_readfirstlane(ei[E + e]);

  const float2* pa = (const float2*)(AB + (size_t)row * 256) + lane;
  const float2* pb = (const float2*)(AB + (size_t)col * 256 + 128) + lane;
  float2 a = *pa;
  float2 b = *pb;
  float2 w2 = ((const float2*)W2)[lane];

  float h0 = a.x + b.x;
  float h1 = a.y + b.y;
  float s0 = h0 / (1.f + __expf(-h0));
  float s1 = h1 / (1.f + __expf(-h1));
  float p = s0 * w2.x + s1 * w2.y;

#pragma unroll
  for (int off = 32; off; off >>= 1) p += __shfl_xor(p, off, 64);

  if (lane == 0) out[e] = p + b2[0];
}

// ---------------------------------------------------------------------------
// Fallback (only if workspace is too small): direct per-edge compute.
// ---------------------------------------------------------------------------
__global__ __launch_bounds__(256) void edge_direct(
    const float* __restrict__ s, const int* __restrict__ ei,
    const float* __restrict__ W1, const float* __restrict__ b1,
    const float* __restrict__ W2, const float* __restrict__ b2,
    float* __restrict__ out, int E) {
  __shared__ float sh[256];
  __shared__ float red[128];
  int e = blockIdx.x;
  int t = threadIdx.x;
  int row = ei[e], col = ei[E + e];
  sh[t] = (t < 128) ? s[(size_t)row * D_S + t] : s[(size_t)col * D_S + (t - 128)];
  __syncthreads();
  if (t < 128) {
    float acc = b1[t];
    const float* w = W1 + (size_t)t * 256;
#pragma unroll 8
    for (int j = 0; j < 256; ++j) acc += sh[j] * w[j];
    red[t] = (acc / (1.f + __expf(-acc))) * W2[t];
  }
  __syncthreads();
  if (t < 64) {
    float x = red[t] + red[t + 64];
#pragma unroll
    for (int off = 32; off; off >>= 1) x += __shfl_xor(x, off, 64);
    if (t == 0) out[e] = x + b2[0];
  }
}

extern "C" void kernel_launch(void* const* d_in, const int* in_sizes, int n_in,
                              void* d_out, int out_size, void* d_ws, size_t ws_size,
                              hipStream_t stream) {
  const float* s  = (const float*)d_in[0];
  const int*   ei = (const int*)d_in[1];
  const float* W1 = (const float*)d_in[2];
  const float* b1 = (const float*)d_in[3];
  const float* W2 = (const float*)d_in[4];
  const float* b2 = (const float*)d_in[5];
  float* out = (float*)d_out;

  int n_nodes = in_sizes[0] / D_S;
  int E = in_sizes[1] / 2;

  size_t need = (size_t)n_nodes * 256 * sizeof(float);
  if (ws_size >= need) {
    float* AB = (float*)d_ws;
    precompute_ab<<<(n_nodes + 63) / 64, 64, 0, stream>>>(s, W1, b1, AB, n_nodes);
    int blocks = (E + 3) / 4;  // 4 waves per 256-thread block, 1 edge per wave
    edge_kernel<<<blocks, 256, 0, stream>>>(ei, AB, W2, b2, out, E);
  } else {
    edge_direct<<<E, 256, 0, stream>>>(s, ei, W1, b1, W2, b2, out, E);
  }
}

// Round 3
// 338.064 us; speedup vs baseline: 1.4637x; 1.4637x over previous
//
#include <hip/hip_runtime.h>
#include <hip/hip_bf16.h>

#define D_S 128

// ---------------------------------------------------------------------------
// Kernel 1: per-node precompute of the fused first layer.
//   AB[n][k]     = dot(W1[k, 0:128],   s[n]) + b1[k]   for k in [0,128)
//   AB[n][128+k] = dot(W1[k, 128:256], s[n])           for k in [0,128)
// Grid: (ceil(n/64), 4). Block = 1 wave = 64 nodes. Each wave computes a
// 64-k chunk (blockIdx.y) for its 64 nodes: 3128 waves total (R2 bug: 782
// waves for 1024 SIMDs -> 9% occupancy). Writes go through an LDS transpose
// so global stores are lane-contiguous (R1 bug: 10x write amplification).
// W1 addresses are wave-uniform (k uniform) -> scalar loads + SGPR-operand FMA.
// ---------------------------------------------------------------------------
__global__ __launch_bounds__(64) void precompute_ab(
    const float* __restrict__ s, const float* __restrict__ W1,
    const float* __restrict__ b1, float* __restrict__ AB, int n_nodes) {
  __shared__ float tile[64][33];  // +1 pad: transposed read is conflict-free
  int lane = threadIdx.x;
  int n0 = blockIdx.x * 64;
  int n = n0 + lane;
  bool valid = (n < n_nodes);
  int nc = valid ? n : 0;

  // Whole s-row in registers (each k uses the full 128-dim row).
  float4 sr[32];
  const float4* sp = (const float4*)(s + (size_t)nc * D_S);
#pragma unroll
  for (int i = 0; i < 32; ++i) sr[i] = sp[i];

#pragma unroll 1
  for (int kc = 0; kc < 2; ++kc) {
    int k0 = blockIdx.y * 64 + kc * 32;
    // ---- compute this thread's 32 outputs for chunk [k0, k0+32) ----
#pragma unroll 1
    for (int kk = 0; kk < 32; kk += 4) {
#pragma unroll
      for (int q = 0; q < 4; ++q) {
        int k = k0 + kk + q;  // wave-uniform
        const float* w = W1 + ((k < D_S) ? (size_t)k * (2 * D_S)
                                         : (size_t)(k - D_S) * (2 * D_S) + D_S);
        float a0 = 0.f, a1 = 0.f, a2 = 0.f, a3 = 0.f;
#pragma unroll
        for (int i = 0; i < 32; ++i) {
          a0 += sr[i].x * w[4 * i + 0];
          a1 += sr[i].y * w[4 * i + 1];
          a2 += sr[i].z * w[4 * i + 2];
          a3 += sr[i].w * w[4 * i + 3];
        }
        float acc = (a0 + a1) + (a2 + a3);
        if (k < D_S) acc += b1[k];
        tile[lane][kk + q] = acc;
      }
    }
    __syncthreads();
    // ---- transposed, coalesced store: lanes 0-31 -> node p (k consecutive),
    //      lanes 32-63 -> node p+1. Two 128B segments per store instr. ----
#pragma unroll
    for (int p = 0; p < 64; p += 2) {
      int hi = lane >> 5;
      int node = n0 + p + hi;
      float v = tile[p + hi][lane & 31];
      if (node < n_nodes) AB[(size_t)node * 256 + k0 + (lane & 31)] = v;
    }
    __syncthreads();
  }
}

// ---------------------------------------------------------------------------
// Kernel 2: per-edge. One wave (64 lanes) per edge.
//   out[e] = sum_k W2[k] * silu(AB[row][k] + AB[col][128+k]) + b2
// Lane l handles k = 2l, 2l+1 (coalesced float2 loads: 512B per row-half).
// ---------------------------------------------------------------------------
__global__ __launch_bounds__(256) void edge_kernel(
    const int* __restrict__ ei, const float* __restrict__ AB,
    const float* __restrict__ W2, const float* __restrict__ b2,
    float* __restrict__ out, int E) {
  int wave = (blockIdx.x * blockDim.x + threadIdx.x) >> 6;
  int lane = threadIdx.x & 63;
  if (wave >= E) return;
  int e = wave;

  int row = __builtin_amdgcn_readfirstlane(ei[e]);
  int col = __builtin_amdgcn_readfirstlane(ei[E + e]);

  const float2* pa = (const float2*)(AB + (size_t)row * 256) + lane;
  const float2* pb = (const float2*)(AB + (size_t)col * 256 + 128) + lane;
  float2 a = *pa;
  float2 b = *pb;
  float2 w2 = ((const float2*)W2)[lane];

  float h0 = a.x + b.x;
  float h1 = a.y + b.y;
  float s0 = h0 / (1.f + __expf(-h0));
  float s1 = h1 / (1.f + __expf(-h1));
  float p = s0 * w2.x + s1 * w2.y;

#pragma unroll
  for (int off = 32; off; off >>= 1) p += __shfl_xor(p, off, 64);

  if (lane == 0) out[e] = p + b2[0];
}

// ---------------------------------------------------------------------------
// Fallback (only if workspace is too small): direct per-edge compute.
// ---------------------------------------------------------------------------
__global__ __launch_bounds__(256) void edge_direct(
    const float* __restrict__ s, const int* __restrict__ ei,
    const float* __restrict__ W1, const float* __restrict__ b1,
    const float* __restrict__ W2, const float* __restrict__ b2,
    float* __restrict__ out, int E) {
  __shared__ float sh[256];
  __shared__ float red[128];
  int e = blockIdx.x;
  int t = threadIdx.x;
  int row = ei[e], col = ei[E + e];
  sh[t] = (t < 128) ? s[(size_t)row * D_S + t] : s[(size_t)col * D_S + (t - 128)];
  __syncthreads();
  if (t < 128) {
    float acc = b1[t];
    const float* w = W1 + (size_t)t * 256;
#pragma unroll 8
    for (int j = 0; j < 256; ++j) acc += sh[j] * w[j];
    red[t] = (acc / (1.f + __expf(-acc))) * W2[t];
  }
  __syncthreads();
  if (t < 64) {
    float x = red[t] + red[t + 64];
#pragma unroll
    for (int off = 32; off; off >>= 1) x += __shfl_xor(x, off, 64);
    if (t == 0) out[e] = x + b2[0];
  }
}

extern "C" void kernel_launch(void* const* d_in, const int* in_sizes, int n_in,
                              void* d_out, int out_size, void* d_ws, size_t ws_size,
                              hipStream_t stream) {
  const float* s  = (const float*)d_in[0];
  const int*   ei = (const int*)d_in[1];
  const float* W1 = (const float*)d_in[2];
  const float* b1 = (const float*)d_in[3];
  const float* W2 = (const float*)d_in[4];
  const float* b2 = (const float*)d_in[5];
  float* out = (float*)d_out;

  int n_nodes = in_sizes[0] / D_S;
  int E = in_sizes[1] / 2;

  size_t need = (size_t)n_nodes * 256 * sizeof(float);
  if (ws_size >= need) {
    float* AB = (float*)d_ws;
    dim3 g1((n_nodes + 63) / 64, 4);
    precompute_ab<<<g1, 64, 0, stream>>>(s, W1, b1, AB, n_nodes);
    int blocks = (E + 3) / 4;  // 4 waves per 256-thread block, 1 edge per wave
    edge_kernel<<<blocks, 256, 0, stream>>>(ei, AB, W2, b2, out, E);
  } else {
    edge_direct<<<E, 256, 0, stream>>>(s, ei, W1, b1, W2, b2, out, E);
  }
}

// Round 4
// 159.250 us; speedup vs baseline: 3.1071x; 2.1228x over previous
//
#include <hip/hip_runtime.h>
#include <hip/hip_bf16.h>

#define D_S 128
#define PAD 132  // 128 + 4: lane stride 4 banks -> conflict-free b128 tile reads

__device__ __forceinline__ unsigned short f32_to_bf16(float f) {
  unsigned int u = __float_as_uint(f);
  return (unsigned short)((u + 0x7FFFu + ((u >> 16) & 1u)) >> 16);  // RN-even
}
__device__ __forceinline__ float bf16_to_f32(unsigned short u) {
  return __uint_as_float(((unsigned int)u) << 16);
}

// ---------------------------------------------------------------------------
// Kernel 1: AB[n][k] = W1cat[k] . s[n] (+ b1[k] for k<128), stored bf16.
// Proper LDS-tiled GEMM. Block = 256 threads, tile M=64 nodes x N=256 k,
// K=128. s-tile staged once; W1 staged per 64-k chunk. Thread (i=t&15,
// j=t>>4) owns nodes {i+16m} x k {j+16n}: 4x4 register micro-tile.
// Per 4 K-steps: 8 ds_read_b128 + 64 FMAs -> FMA-bound (R3 bug: compiler
// re-read s from L1 per k; VGPR_Count=112 proved sr[] never stayed in regs).
// Output bounced through LDS so global stores are lane-contiguous bf16x4.
// ---------------------------------------------------------------------------
__global__ __launch_bounds__(256, 2) void precompute_ab(
    const float* __restrict__ s, const float* __restrict__ W1,
    const float* __restrict__ b1, unsigned short* __restrict__ AB,
    int n_nodes) {
  __shared__ __align__(16) float s_tile[64][PAD];
  __shared__ __align__(16) float w_tile[64][PAD];
  __shared__ __align__(16) unsigned short o_tile[64][68];

  int t = threadIdx.x;
  int n0 = blockIdx.x * 64;

  // ---- stage s_tile[64][128] (coalesced: lanes cover one row's 512B) ----
#pragma unroll
  for (int rep = 0; rep < 8; ++rep) {
    int linear = t + rep * 256;          // 2048 float4 slots
    int row = linear >> 5;
    int c4 = (linear & 31) * 4;
    int gn = n0 + row;
    float4 v = make_float4(0.f, 0.f, 0.f, 0.f);
    if (gn < n_nodes) v = *(const float4*)(s + (size_t)gn * D_S + c4);
    *(float4*)&s_tile[row][c4] = v;
  }

  int i = t & 15;   // node group: rows {i, i+16, i+32, i+48}
  int j = t >> 4;   // k group:    cols {j, j+16, j+32, j+48} within chunk

#pragma unroll 1
  for (int nc = 0; nc < 4; ++nc) {
    // ---- stage w_tile: row kt holds concat-view row k = nc*64+kt ----
#pragma unroll
    for (int rep = 0; rep < 8; ++rep) {
      int linear = t + rep * 256;
      int kt = linear >> 5;
      int c4 = (linear & 31) * 4;
      int k = nc * 64 + kt;
      const float* src =
          W1 + ((k < D_S) ? (size_t)k * (2 * D_S) : (size_t)(k - D_S) * (2 * D_S) + D_S);
      *(float4*)&w_tile[kt][c4] = *(const float4*)(src + c4);
    }
    __syncthreads();

    // ---- 4x4 micro-tile GEMM over K=128 ----
    float acc[4][4] = {};
#pragma unroll 4
    for (int kk = 0; kk < 128; kk += 4) {
      float4 sa[4], wb[4];
#pragma unroll
      for (int m = 0; m < 4; ++m) sa[m] = *(const float4*)&s_tile[i + 16 * m][kk];
#pragma unroll
      for (int n = 0; n < 4; ++n) wb[n] = *(const float4*)&w_tile[j + 16 * n][kk];
#pragma unroll
      for (int m = 0; m < 4; ++m)
#pragma unroll
        for (int n = 0; n < 4; ++n) {
          acc[m][n] = fmaf(sa[m].x, wb[n].x, acc[m][n]);
          acc[m][n] = fmaf(sa[m].y, wb[n].y, acc[m][n]);
          acc[m][n] = fmaf(sa[m].z, wb[n].z, acc[m][n]);
          acc[m][n] = fmaf(sa[m].w, wb[n].w, acc[m][n]);
        }
    }

    // bias on the A-half (k < 128 <=> nc < 2)
    if (nc < 2) {
#pragma unroll
      for (int n = 0; n < 4; ++n) {
        float bv = b1[nc * 64 + j + 16 * n];
#pragma unroll
        for (int m = 0; m < 4; ++m) acc[m][n] += bv;
      }
    }

    // ---- bounce through LDS for coalesced bf16 stores ----
#pragma unroll
    for (int m = 0; m < 4; ++m)
#pragma unroll
      for (int n = 0; n < 4; ++n)
        o_tile[i + 16 * m][j + 16 * n] = f32_to_bf16(acc[m][n]);
    __syncthreads();

#pragma unroll
    for (int rep = 0; rep < 4; ++rep) {
      int linear = t + rep * 256;        // 1024 chunks of 4 bf16
      int row = linear >> 4;
      int cg = (linear & 15) * 4;
      int gn = n0 + row;
      if (gn < n_nodes) {
        ushort4 v = *(const ushort4*)&o_tile[row][cg];
        *(ushort4*)(AB + (size_t)gn * 256 + nc * 64 + cg) = v;
      }
    }
    __syncthreads();  // o_tile/w_tile free before next chunk's writes
  }
}

// ---------------------------------------------------------------------------
// Kernel 2: per-edge, bf16 table. 2 edges per wave (32 lanes each):
//   out[e] = sum_k W2[k] * silu(A[row][k] + B[col][k]) + b2
// Lane sub (0..31) handles k = 4*sub..4*sub+3 via one ushort4 (8B) load per
// half-row: 32 lanes x 8B = 256B contiguous -> fully coalesced.
// ---------------------------------------------------------------------------
__global__ __launch_bounds__(256) void edge_kernel(
    const int* __restrict__ ei, const unsigned short* __restrict__ AB,
    const float* __restrict__ W2, const float* __restrict__ b2,
    float* __restrict__ out, int E) {
  int t = threadIdx.x;
  int wave = (blockIdx.x * 256 + t) >> 6;
  int half = (t >> 5) & 1;
  int sub = t & 31;
  int e = wave * 2 + half;
  if (e >= E) e = E - 1;  // duplicate tail edge: deterministic, same value

  int row = ei[e];
  int col = ei[E + e];

  ushort4 ua = *((const ushort4*)(AB + (size_t)row * 256) + sub);
  ushort4 ub = *((const ushort4*)(AB + (size_t)col * 256 + 128) + sub);
  float4 w2 = ((const float4*)W2)[sub];

  float h0 = bf16_to_f32(ua.x) + bf16_to_f32(ub.x);
  float h1 = bf16_to_f32(ua.y) + bf16_to_f32(ub.y);
  float h2 = bf16_to_f32(ua.z) + bf16_to_f32(ub.z);
  float h3 = bf16_to_f32(ua.w) + bf16_to_f32(ub.w);

  float p;
  {
    float s0 = __fdividef(h0, 1.f + __expf(-h0));
    float s1 = __fdividef(h1, 1.f + __expf(-h1));
    float s2 = __fdividef(h2, 1.f + __expf(-h2));
    float s3 = __fdividef(h3, 1.f + __expf(-h3));
    p = s0 * w2.x + s1 * w2.y + s2 * w2.z + s3 * w2.w;
  }

#pragma unroll
  for (int off = 16; off; off >>= 1) p += __shfl_xor(p, off, 64);

  if (sub == 0) out[e] = p + b2[0];
}

// ---------------------------------------------------------------------------
// Fallback (workspace too small): direct per-edge compute, fp32.
// ---------------------------------------------------------------------------
__global__ __launch_bounds__(256) void edge_direct(
    const float* __restrict__ s, const int* __restrict__ ei,
    const float* __restrict__ W1, const float* __restrict__ b1,
    const float* __restrict__ W2, const float* __restrict__ b2,
    float* __restrict__ out, int E) {
  __shared__ float sh[256];
  __shared__ float red[128];
  int e = blockIdx.x;
  int t = threadIdx.x;
  int row = ei[e], col = ei[E + e];
  sh[t] = (t < 128) ? s[(size_t)row * D_S + t] : s[(size_t)col * D_S + (t - 128)];
  __syncthreads();
  if (t < 128) {
    float acc = b1[t];
    const float* w = W1 + (size_t)t * 256;
#pragma unroll 8
    for (int jj = 0; jj < 256; ++jj) acc += sh[jj] * w[jj];
    red[t] = (acc / (1.f + __expf(-acc))) * W2[t];
  }
  __syncthreads();
  if (t < 64) {
    float x = red[t] + red[t + 64];
#pragma unroll
    for (int off = 32; off; off >>= 1) x += __shfl_xor(x, off, 64);
    if (t == 0) out[e] = x + b2[0];
  }
}

extern "C" void kernel_launch(void* const* d_in, const int* in_sizes, int n_in,
                              void* d_out, int out_size, void* d_ws, size_t ws_size,
                              hipStream_t stream) {
  const float* s  = (const float*)d_in[0];
  const int*   ei = (const int*)d_in[1];
  const float* W1 = (const float*)d_in[2];
  const float* b1 = (const float*)d_in[3];
  const float* W2 = (const float*)d_in[4];
  const float* b2 = (const float*)d_in[5];
  float* out = (float*)d_out;

  int n_nodes = in_sizes[0] / D_S;
  int E = in_sizes[1] / 2;

  size_t need = (size_t)n_nodes * 256 * sizeof(unsigned short);
  if (ws_size >= need) {
    unsigned short* AB = (unsigned short*)d_ws;
    precompute_ab<<<(n_nodes + 63) / 64, 256, 0, stream>>>(s, W1, b1, AB, n_nodes);
    int blocks = (E + 7) / 8;  // 4 waves/block, 2 edges/wave
    edge_kernel<<<blocks, 256, 0, stream>>>(ei, AB, W2, b2, out, E);
  } else {
    edge_direct<<<E, 256, 0, stream>>>(s, ei, W1, b1, W2, b2, out, E);
  }
}

// Round 5
// 89.450 us; speedup vs baseline: 5.5317x; 1.7803x over previous
//
#include <hip/hip_runtime.h>
#include <hip/hip_bf16.h>

#define D_S 128

typedef short bf16x8 __attribute__((ext_vector_type(8)));
typedef float f32x4 __attribute__((ext_vector_type(4)));

__device__ __forceinline__ unsigned short f32_to_bf16(float f) {
  unsigned int u = __float_as_uint(f);
  return (unsigned short)((u + 0x7FFFu + ((u >> 16) & 1u)) >> 16);  // RN-even
}
__device__ __forceinline__ unsigned int pack2_bf16(float lo, float hi) {
  return (unsigned int)f32_to_bf16(lo) | ((unsigned int)f32_to_bf16(hi) << 16);
}
__device__ __forceinline__ bf16x8 cvt_frag(float4 x, float4 y) {
  union { bf16x8 v; unsigned int u[4]; } r;
  r.u[0] = pack2_bf16(x.x, x.y);
  r.u[1] = pack2_bf16(x.z, x.w);
  r.u[2] = pack2_bf16(y.x, y.y);
  r.u[3] = pack2_bf16(y.z, y.w);
  return r.v;
}

// ---------------------------------------------------------------------------
// Kernel 1 (MFMA): AB[n][j] = Wc[j] . s[n] (+ b1[j] for j<128), bf16 out.
// C = S[50000x128] * Wc^T[128x256]; mfma_f32_16x16x32_bf16.
// Block = 256 thr (4 waves), tile = 64 nodes x 256 j. Wave w owns j-slice
// [32w,32w+32) of each 128-j chunk (2 chunks: A-half then B-half of Wc).
// A/B fragments loaded DIRECTLY from global fp32 + in-reg RNE cvt to bf16
// (lane l: row/col = l&15, k-slots = (l>>4)*8+e; k-permutation is identical
// for A and B packing -> result exact regardless of HW k-order).
// D layout (m89-verified): col = lane&15, row = (lane>>4)*4 + reg.
// Output bounced via o_tile so global stores are 16B-contiguous per row.
// R4 bug fixed: fp32 VALU GEMM @ 38% VALUBusy, 2 blk/CU -> MFMA + tiny LDS.
// ---------------------------------------------------------------------------
__global__ __launch_bounds__(256, 1) void precompute_mfma(
    const float* __restrict__ s, const float* __restrict__ W1,
    const float* __restrict__ b1, unsigned short* __restrict__ AB,
    int n_nodes) {
  __shared__ __align__(16) unsigned short o_tile[64][136];  // 17.4 KB
  int t = threadIdx.x;
  int wv = t >> 6, lane = t & 63;
  int lr = lane & 15, lc = lane >> 4;
  int n0 = blockIdx.x * 64;

  // A fragments: 4 m-tiles x 4 k-steps (K=128), reused for both chunks.
  bf16x8 afrag[4][4];
#pragma unroll
  for (int m = 0; m < 4; ++m) {
    int r = n0 + m * 16 + lr;
    if (r > n_nodes - 1) r = n_nodes - 1;  // clamp; junk rows masked at store
    const float* ap = s + (size_t)r * D_S + lc * 8;
#pragma unroll
    for (int ks = 0; ks < 4; ++ks) {
      float4 x = *(const float4*)(ap + ks * 32);
      float4 y = *(const float4*)(ap + ks * 32 + 4);
      afrag[m][ks] = cvt_frag(x, y);
    }
  }

#pragma unroll 1
  for (int chunk = 0; chunk < 2; ++chunk) {
    f32x4 acc[4][2] = {};
    // Wc row j (chunk c): c==0 -> W1[j][0:128]; c==1 -> W1[j][128:256].
    const float* wbase =
        W1 + (size_t)(wv * 32 + lr) * (2 * D_S) + chunk * D_S + lc * 8;
#pragma unroll
    for (int ks = 0; ks < 4; ++ks) {
      bf16x8 bfr[2];
#pragma unroll
      for (int nt = 0; nt < 2; ++nt) {
        const float* bp = wbase + (size_t)nt * 16 * (2 * D_S) + ks * 32;
        float4 x = *(const float4*)bp;
        float4 y = *(const float4*)(bp + 4);
        bfr[nt] = cvt_frag(x, y);
      }
#pragma unroll
      for (int m = 0; m < 4; ++m)
#pragma unroll
        for (int nt = 0; nt < 2; ++nt)
          acc[m][nt] = __builtin_amdgcn_mfma_f32_16x16x32_bf16(
              afrag[m][ks], bfr[nt], acc[m][nt], 0, 0, 0);
    }

    if (chunk == 0) {  // bias folds into the A-half only
#pragma unroll
      for (int nt = 0; nt < 2; ++nt) {
        float bv = b1[wv * 32 + nt * 16 + lr];
#pragma unroll
        for (int m = 0; m < 4; ++m)
#pragma unroll
          for (int r = 0; r < 4; ++r) acc[m][nt][r] += bv;
      }
    }

    // D -> LDS (bf16), then coalesced copy-out (16 thr cover one 256B row).
#pragma unroll
    for (int m = 0; m < 4; ++m)
#pragma unroll
      for (int nt = 0; nt < 2; ++nt) {
        int colc = wv * 32 + nt * 16 + lr;
#pragma unroll
        for (int r = 0; r < 4; ++r)
          o_tile[m * 16 + lc * 4 + r][colc] = f32_to_bf16(acc[m][nt][r]);
      }
    __syncthreads();
#pragma unroll
    for (int rep = 0; rep < 4; ++rep) {
      int idx = t + rep * 256;        // 1024 chunks of 8 bf16
      int rowi = idx >> 4, cg = (idx & 15) * 8;
      int gn = n0 + rowi;
      if (gn < n_nodes) {
        uint4 v = *(const uint4*)&o_tile[rowi][cg];
        *(uint4*)(AB + (size_t)gn * 256 + chunk * D_S + cg) = v;
      }
    }
    __syncthreads();
  }
}

// ---------------------------------------------------------------------------
// Kernel 2: per-edge. 8 edges/wave, 8 lanes/edge, 16 k/lane.
//   out[e] = sum_k W2[k] * silu(A[row][k] + B[col][k]) + b2
// Per lane: 2x dwordx4 bf16 per half-row (8 lanes x 32B = 256B = exactly one
// half-row, fully coalesced). 3-step shfl reduce. 32-bit voffsets (table is
// 25.6MB). Raw v_exp/v_rcp via builtins: ~7 VALU + 2 transcendental per k.
// R4 bug fixed: 4k/lane + 5-step reduce + 64b addr math -> VALUBusy 99%.
// ---------------------------------------------------------------------------
__device__ __forceinline__ float silu2(unsigned int ua, unsigned int ub,
                                       float wlo, float whi) {
  float h0 = __uint_as_float(ua << 16) + __uint_as_float(ub << 16);
  float h1 = __uint_as_float(ua & 0xFFFF0000u) + __uint_as_float(ub & 0xFFFF0000u);
  float e0 = __builtin_amdgcn_exp2f(h0 * -1.442695041f);
  float e1 = __builtin_amdgcn_exp2f(h1 * -1.442695041f);
  float r0 = __builtin_amdgcn_rcpf(1.f + e0);
  float r1 = __builtin_amdgcn_rcpf(1.f + e1);
  return h0 * r0 * wlo + h1 * r1 * whi;
}

__global__ __launch_bounds__(256) void edge_kernel(
    const int* __restrict__ ei, const unsigned short* __restrict__ AB,
    const float* __restrict__ W2, const float* __restrict__ b2,
    float* __restrict__ out, int E) {
  int t = threadIdx.x;
  int wv = (blockIdx.x << 2) + (t >> 6);
  int lane = t & 63;
  int g = lane >> 3, sub = lane & 7;
  int e = wv * 8 + g;
  if (e >= E) e = E - 1;  // duplicate tail edge: deterministic, same value

  int row = ei[e];
  int col = ei[E + e];

  unsigned int offA = ((unsigned int)row << 8) + (sub << 4);
  unsigned int offB = ((unsigned int)col << 8) + 128 + (sub << 4);
  uint4 a0 = *(const uint4*)(AB + offA);
  uint4 a1 = *(const uint4*)(AB + offA + 8);
  uint4 b0 = *(const uint4*)(AB + offB);
  uint4 b1v = *(const uint4*)(AB + offB + 8);

  const float4* wp = (const float4*)(W2 + (sub << 4));
  float4 w0 = wp[0], w1 = wp[1], w2 = wp[2], w3 = wp[3];

  float p = 0.f;
  p += silu2(a0.x, b0.x, w0.x, w0.y);
  p += silu2(a0.y, b0.y, w0.z, w0.w);
  p += silu2(a0.z, b0.z, w1.x, w1.y);
  p += silu2(a0.w, b0.w, w1.z, w1.w);
  p += silu2(a1.x, b1v.x, w2.x, w2.y);
  p += silu2(a1.y, b1v.y, w2.z, w2.w);
  p += silu2(a1.z, b1v.z, w3.x, w3.y);
  p += silu2(a1.w, b1v.w, w3.z, w3.w);

#pragma unroll
  for (int off = 1; off < 8; off <<= 1) p += __shfl_xor(p, off, 64);

  if (sub == 0) out[e] = p + b2[0];
}

// ---------------------------------------------------------------------------
// Fallback (workspace too small): direct per-edge compute, fp32.
// ---------------------------------------------------------------------------
__global__ __launch_bounds__(256) void edge_direct(
    const float* __restrict__ s, const int* __restrict__ ei,
    const float* __restrict__ W1, const float* __restrict__ b1,
    const float* __restrict__ W2, const float* __restrict__ b2,
    float* __restrict__ out, int E) {
  __shared__ float sh[256];
  __shared__ float red[128];
  int e = blockIdx.x;
  int t = threadIdx.x;
  int row = ei[e], col = ei[E + e];
  sh[t] = (t < 128) ? s[(size_t)row * D_S + t] : s[(size_t)col * D_S + (t - 128)];
  __syncthreads();
  if (t < 128) {
    float acc = b1[t];
    const float* w = W1 + (size_t)t * 256;
#pragma unroll 8
    for (int jj = 0; jj < 256; ++jj) acc += sh[jj] * w[jj];
    red[t] = (acc / (1.f + __expf(-acc))) * W2[t];
  }
  __syncthreads();
  if (t < 64) {
    float x = red[t] + red[t + 64];
#pragma unroll
    for (int off = 32; off; off >>= 1) x += __shfl_xor(x, off, 64);
    if (t == 0) out[e] = x + b2[0];
  }
}

extern "C" void kernel_launch(void* const* d_in, const int* in_sizes, int n_in,
                              void* d_out, int out_size, void* d_ws, size_t ws_size,
                              hipStream_t stream) {
  const float* s  = (const float*)d_in[0];
  const int*   ei = (const int*)d_in[1];
  const float* W1 = (const float*)d_in[2];
  const float* b1 = (const float*)d_in[3];
  const float* W2 = (const float*)d_in[4];
  const float* b2 = (const float*)d_in[5];
  float* out = (float*)d_out;

  int n_nodes = in_sizes[0] / D_S;
  int E = in_sizes[1] / 2;

  size_t need = (size_t)n_nodes * 256 * sizeof(unsigned short);
  if (ws_size >= need) {
    unsigned short* AB = (unsigned short*)d_ws;
    precompute_mfma<<<(n_nodes + 63) / 64, 256, 0, stream>>>(s, W1, b1, AB, n_nodes);
    int blocks = (E + 31) / 32;  // 4 waves/block, 8 edges/wave
    edge_kernel<<<blocks, 256, 0, stream>>>(ei, AB, W2, b2, out, E);
  } else {
    edge_direct<<<E, 256, 0, stream>>>(s, ei, W1, b1, W2, b2, out, E);
  }
}